// Round 1
// baseline (1175.934 us; speedup 1.0000x reference)
//
#include <hip/hip_runtime.h>

// ---------------------------------------------------------------------------
// RNNCell encoder: seq=512, batch=512, H=IN=300.
//   Phase 0 (prep):   convert W_ih, W_hh to bf16, zero-padded to [320][320];
//                     bias_sum[n] = b_ih[n]+b_hh[n].
//   Phase 1 (xproj):  xp[s*512+b][n] = sum_k in[s,b,k]*W_ih[n,k] + bias_sum[n]
//                     bf16 MFMA 32x32x16, BM=128, BN=320, K=304 (19 ksteps).
//   Phase 2 (recur):  32 WGs x 512 thr; WG owns 16 batch rows for all 512
//                     steps. W_hh B-fragments register-resident (no grid sync,
//                     recurrence independent per batch row). h kept bf16 in
//                     LDS (16 x 328), MFMA 16x16x32.
// ---------------------------------------------------------------------------

typedef unsigned short u16;
typedef unsigned int   u32;
typedef __attribute__((ext_vector_type(8)))  short bf16x8;
typedef __attribute__((ext_vector_type(4)))  float f32x4;
typedef __attribute__((ext_vector_type(16))) float f32x16;

#define HID 300
#define KP  320           // padded K / N
#define SEQ 512
#define BZ  512
#define MTOT (SEQ*BZ)     // 262144 rows of x_proj

__device__ __forceinline__ u16 f2bf(float f) {
    u32 u = __float_as_uint(f);
    return (u16)((u + 0x7FFFu + ((u >> 16) & 1u)) >> 16);  // RNE
}
__device__ __forceinline__ float bf2f(u16 h) {
    return __uint_as_float((u32)h << 16);
}
__device__ __forceinline__ float tanh_fast(float x) {
    // tanh(x) = 1 - 2/(exp(2x)+1); exp(2x) = exp2(x*2/ln2)
    float e = __builtin_amdgcn_exp2f(x * 2.8853900817779268f);
    float r = __builtin_amdgcn_rcpf(e + 1.0f);
    return __builtin_fmaf(-2.0f, r, 1.0f);
}

// ---------------------------------------------------------------------------
// Phase 0: weight conversion / padding. grid 320 x 320 threads.
__global__ void prep_kernel(const float* __restrict__ wih,
                            const float* __restrict__ whh,
                            const float* __restrict__ bih,
                            const float* __restrict__ bhh,
                            u16* __restrict__ wihp, u16* __restrict__ whhp,
                            float* __restrict__ bias) {
    int n = blockIdx.x, k = threadIdx.x;
    bool v = (n < HID) && (k < HID);
    int src = n * HID + k, dst = n * KP + k;
    wihp[dst] = v ? f2bf(wih[src]) : (u16)0;
    whhp[dst] = v ? f2bf(whh[src]) : (u16)0;
    if (k == 0) bias[n] = (n < HID) ? (bih[n] + bhh[n]) : 0.0f;
}

// ---------------------------------------------------------------------------
// Phase 1: xp = in @ W_ih^T + bias, bf16 out. 2048 WGs x 512 thr, BM=128.
__global__ __launch_bounds__(512, 2) void xproj_kernel(
    const float* __restrict__ in, const u16* __restrict__ wihp,
    const float* __restrict__ bias, u16* __restrict__ xp) {
    // LDS: A bf16 [128][20] (stride 20 el = 40B, 2-way-free banks)
    //      B bf16 [320][2 chunks of 8, XOR-swizzled] stride 40 el
    __shared__ __align__(16) u16 As[128 * 20];
    __shared__ __align__(16) u16 Bs[320 * 40];

    const int tid = threadIdx.x;
    const int w = tid >> 6, l = tid & 63;
    const int l5 = l >> 5, l31 = l & 31;
    const int m0 = blockIdx.x * 128;
    const int mt = w & 3;        // M-tile (32 rows) of this wave
    const int par = w >> 2;      // 0 -> even N-tiles, 1 -> odd

    f32x16 acc[5];
#pragma unroll
    for (int j = 0; j < 5; ++j)
#pragma unroll
        for (int r = 0; r < 16; ++r) acc[j][r] = 0.0f;

    // staging roles
    const int ar = tid >> 2, aq = tid & 3;       // A: 128 rows x 4 f32x4 chunks
    const int bn = tid >> 1, bc = tid & 1;       // B: rows 0..255 (+256 if tid<128)

    // prefetch ks=0
    f32x4 aP;
    bf16x8 bP0, bP1;
    {
        aP = *(const f32x4*)(in + (m0 + ar) * HID + aq * 4);   // k<300 always here
        bP0 = *(const bf16x8*)(wihp + bn * KP + bc * 8);
        if (tid < 128) bP1 = *(const bf16x8*)(wihp + (bn + 256) * KP + bc * 8);
    }

#pragma unroll 1
    for (int ks = 0; ks < 19; ++ks) {            // K = 19*16 = 304 (>=300)
        __syncthreads();                          // prev readers done
        // write A (convert fp32 -> bf16)
        {
            u32 w0 = (u32)f2bf(aP[0]) | ((u32)f2bf(aP[1]) << 16);
            u32 w1 = (u32)f2bf(aP[2]) | ((u32)f2bf(aP[3]) << 16);
            u32* p = (u32*)&As[ar * 20 + aq * 4];
            p[0] = w0; p[1] = w1;
        }
        // write B (chunk-XOR swizzle: chunk' = c ^ (n&1))
        *(bf16x8*)&Bs[bn * 40 + ((bc ^ (bn & 1)) * 8)] = bP0;
        if (tid < 128)
            *(bf16x8*)&Bs[(bn + 256) * 40 + ((bc ^ (bn & 1)) * 8)] = bP1;

        if (ks < 18) {
            int gk = (ks + 1) * 16 + aq * 4;
            if (gk < HID) {
                aP = *(const f32x4*)(in + (m0 + ar) * HID + gk);
            } else {
                aP[0] = aP[1] = aP[2] = aP[3] = 0.0f;
            }
            bP0 = *(const bf16x8*)(wihp + bn * KP + (ks + 1) * 16 + bc * 8);
            if (tid < 128)
                bP1 = *(const bf16x8*)(wihp + (bn + 256) * KP + (ks + 1) * 16 + bc * 8);
        }
        __syncthreads();                          // staged data visible

        bf16x8 a = *(const bf16x8*)&As[(mt * 32 + l31) * 20 + l5 * 8];
#pragma unroll
        for (int j = 0; j < 5; ++j) {
            int nt = 2 * j + par;
            bf16x8 b = *(const bf16x8*)&Bs[(nt * 32 + l31) * 40 + ((l5 ^ (l31 & 1)) * 8)];
            acc[j] = __builtin_amdgcn_mfma_f32_32x32x16_bf16(a, b, acc[j], 0, 0, 0);
        }
    }

    // epilogue: C layout (32x32): col = l&31, row = (reg&3) + 8*(reg>>2) + 4*(l>>5)
#pragma unroll
    for (int j = 0; j < 5; ++j) {
        int nt = 2 * j + par;
        int n = nt * 32 + l31;
        if (n < HID) {
            float bs = bias[n];
#pragma unroll
            for (int reg = 0; reg < 16; ++reg) {
                int row = (reg & 3) + 8 * (reg >> 2) + 4 * l5;
                float v = acc[j][reg] + bs;
                xp[(m0 + mt * 32 + row) * HID + n] = f2bf(v);
            }
        }
    }
}

// ---------------------------------------------------------------------------
// Phase 2: recurrence. 32 WGs x 512 thr; WG owns batch rows [b0, b0+16).
__global__ __launch_bounds__(512, 2) void rnn_recur_kernel(
    const u16* __restrict__ xp, const u16* __restrict__ whhp,
    float* __restrict__ out) {
    __shared__ __align__(16) u16 hbuf[16 * 328];   // h (bf16), row stride 328

    const int tid = threadIdx.x;
    const int w = tid >> 6, l = tid & 63;
    const int b0 = blockIdx.x * 16;
    const int col = l & 15, kq = l >> 4;
    const bool has3 = (w < 4);
    const int nt0 = w, nt1 = w + 8, nt2 = w + 16;  // nt2 only for waves 0-3

    // zero h0 (and padding)
    for (int i = tid; i < (16 * 328) / 2; i += 512) ((u32*)hbuf)[i] = 0;

    // register-resident W_hh B-fragments: B[k][n] = W_hh[n][k]
    bf16x8 Bf0[10], Bf1[10], Bf2[10];
#pragma unroll
    for (int ks = 0; ks < 10; ++ks) {
        Bf0[ks] = *(const bf16x8*)(whhp + (nt0 * 16 + col) * KP + ks * 32 + kq * 8);
        Bf1[ks] = *(const bf16x8*)(whhp + (nt1 * 16 + col) * KP + ks * 32 + kq * 8);
        if (has3)
            Bf2[ks] = *(const bf16x8*)(whhp + (nt2 * 16 + col) * KP + ks * 32 + kq * 8);
    }

    // per-thread xp offsets (-1 = padded column) and hbuf write offsets
    int xoff[12], hoff[12];
#pragma unroll
    for (int i = 0; i < 3; ++i) {
        int nt = (i == 0) ? nt0 : ((i == 1) ? nt1 : nt2);
        int n = nt * 16 + col;
#pragma unroll
        for (int r = 0; r < 4; ++r) {
            xoff[i * 4 + r] = (n < HID) ? ((b0 + kq * 4 + r) * HID + n) : -1;
            hoff[i * 4 + r] = (n < KP) ? ((kq * 4 + r) * 328 + n) : -1;
        }
    }

    // preload xp for t=0
    u16 xc[12];
#pragma unroll
    for (int q = 0; q < 12; ++q) {
        u16 v = 0;
        if (xoff[q] >= 0) v = xp[xoff[q]];
        xc[q] = v;
    }

    __syncthreads();

#pragma unroll 1
    for (int t = 0; t < SEQ; ++t) {
        // prefetch next step's xp (hidden under the MFMAs)
        const int tn = (t < SEQ - 1) ? (t + 1) : (SEQ - 1);
        const int tbase = tn * (BZ * HID);
        u16 xn[12];
#pragma unroll
        for (int q = 0; q < 12; ++q) {
            u16 v = 0;
            if (xoff[q] >= 0) v = xp[tbase + xoff[q]];
            xn[q] = v;
        }

        f32x4 a0, a1, a2;
#pragma unroll
        for (int r = 0; r < 4; ++r) { a0[r] = 0.f; a1[r] = 0.f; a2[r] = 0.f; }

#pragma unroll
        for (int ks = 0; ks < 10; ++ks) {
            // A-frag: lane l holds h[row = l&15][k = ks*32 + (l>>4)*8 + j]
            bf16x8 av = *(const bf16x8*)&hbuf[col * 328 + ks * 32 + kq * 8];
            a0 = __builtin_amdgcn_mfma_f32_16x16x32_bf16(av, Bf0[ks], a0, 0, 0, 0);
            a1 = __builtin_amdgcn_mfma_f32_16x16x32_bf16(av, Bf1[ks], a1, 0, 0, 0);
            if (has3)
                a2 = __builtin_amdgcn_mfma_f32_16x16x32_bf16(av, Bf2[ks], a2, 0, 0, 0);
        }
        __syncthreads();   // all reads of h_t done before overwriting

        // h_{t+1} = tanh(acc + xp); padded cols have acc==0, xc==0 -> tanh(0)=0
#pragma unroll
        for (int r = 0; r < 4; ++r) {
            float c0 = a0[r] + bf2f(xc[r]);
            if (hoff[r] >= 0) hbuf[hoff[r]] = f2bf(tanh_fast(c0));
            float c1 = a1[r] + bf2f(xc[4 + r]);
            if (hoff[4 + r] >= 0) hbuf[hoff[4 + r]] = f2bf(tanh_fast(c1));
            float c2 = a2[r] + bf2f(xc[8 + r]);
            if (hoff[8 + r] >= 0) hbuf[hoff[8 + r]] = f2bf(tanh_fast(c2));
        }
        __syncthreads();   // h_{t+1} visible for next step's reads

#pragma unroll
        for (int q = 0; q < 12; ++q) xc[q] = xn[q];
    }

    // write final h (fp32)
    for (int i = tid; i < 16 * HID; i += 512) {
        int row = i / HID, n = i - row * HID;
        out[(b0 + row) * HID + n] = bf2f(hbuf[row * 328 + n]);
    }
}

// ---------------------------------------------------------------------------
extern "C" void kernel_launch(void* const* d_in, const int* in_sizes, int n_in,
                              void* d_out, int out_size, void* d_ws, size_t ws_size,
                              hipStream_t stream) {
    const float* in  = (const float*)d_in[0];   // [512,512,300]
    const float* wih = (const float*)d_in[1];   // [300,300]
    const float* whh = (const float*)d_in[2];   // [300,300]
    const float* bih = (const float*)d_in[3];   // [300]
    const float* bhh = (const float*)d_in[4];   // [300]

    char* ws = (char*)d_ws;
    const size_t XP_BYTES = (size_t)MTOT * HID * sizeof(u16);   // 157,286,400
    u16*   xpb  = (u16*)ws;
    u16*   wihp = (u16*)(ws + XP_BYTES);                         // 320*320*2
    u16*   whhp = (u16*)(ws + XP_BYTES + (size_t)KP * KP * 2);
    float* bias = (float*)(ws + XP_BYTES + 2 * (size_t)KP * KP * 2);

    prep_kernel<<<KP, KP, 0, stream>>>(wih, whh, bih, bhh, wihp, whhp, bias);
    xproj_kernel<<<MTOT / 128, 512, 0, stream>>>(in, wihp, bias, xpb);
    rnn_recur_kernel<<<BZ / 16, 512, 0, stream>>>(xpb, whhp, (float*)d_out);
}